// Round 1
// baseline (358.643 us; speedup 1.0000x reference)
//
#include <hip/hip_runtime.h>
#include <hip/hip_bf16.h>

// Swin window self-attention, fused. R6: zero-LDS / zero-barrier restructure.
//  - one 64-thread block (1 wave) per (window, head); waves fully independent
//  - projections computed transposed (A=W, B=X) and QK^T swapped (A=K, B=Q):
//    softmax reduction axis lands on quads (2 shfl_xor), query m lands on l
//  - all D-layout -> frag-layout fixups are in-register "quad-regroups"
//    (2 ds_bpermute + 1 cndmask per packed bf16 pair); no LDS, no barriers
//  - X reloaded from global per projection (L1/L2-hot) to keep VGPR <= 128
//    => __launch_bounds__(64,4): target 16 waves/CU vs 12 before
//  - W pre-packed to bf16 in exact frag layout in workspace; bias table
//    pre-gathered transposed (bias_t[h][n][m], zero-padded to 64x64)
//  - V bias folded into epilogue: O += bv (softmax rows sum to 1)

#define SEQ 49
#define CH 128
#define NH 4
#define DHD 32
#define NTAB 169

typedef __hip_bfloat16 bf16;
typedef __attribute__((ext_vector_type(8))) short bf16x8;  // 8 bf16 = 4 VGPRs
typedef __attribute__((ext_vector_type(4))) float f32x4;

#define WP_FRAGS (3*NH*2*4*64)           // 6144 frags of 8 bf16
#define WP_BYTES (WP_FRAGS*8*2)          // 98304
#define BIAS_ELEMS (NH*64*64)            // 16384
#define BIAS_BYTES (BIAS_ELEMS*4)        // 65536
#define WS_NEED ((size_t)(WP_BYTES + BIAS_BYTES))  // 163840

__device__ __forceinline__ bf16x8 pack8(float4 a, float4 b) {
    alignas(16) bf16 t[8] = {
        __float2bfloat16(a.x), __float2bfloat16(a.y),
        __float2bfloat16(a.z), __float2bfloat16(a.w),
        __float2bfloat16(b.x), __float2bfloat16(b.y),
        __float2bfloat16(b.z), __float2bfloat16(b.w)};
    return *(const bf16x8*)t;
}

__device__ __forceinline__ unsigned pk2(float lo, float hi) {
    union { bf16 h[2]; unsigned u; } r;
    r.h[0] = __float2bfloat16(lo);
    r.h[1] = __float2bfloat16(hi);
    return r.u;
}

// Quad-regroup: D-layout tiles give each lane (q,l) values at k = 16t + 4q + r
// (r=0..3, packed as bf16 pairs pkT_p = pair p of tile t). Frag layout wants
// k = 8q + jj (jj=0..7). Word pi of the frag holds pair (8q+2pi, 8q+2pi+1),
// whose owner is lane (2(q&1) + (pi>>1))*16 + l in tile t = q>>1:
//   srcA = (q&1)*32 + l (pi<2), srcB = srcA+16 (pi>=2), hiT = (q>>1).
__device__ __forceinline__ bf16x8 regroup(unsigned pk0_0, unsigned pk0_1,
                                          unsigned pk1_0, unsigned pk1_1,
                                          int srcA, int srcB, bool hiT) {
    union { unsigned u[4]; bf16x8 v; } o;
    unsigned a0 = (unsigned)__shfl((int)pk0_0, srcA);
    unsigned b0 = (unsigned)__shfl((int)pk1_0, srcA);
    unsigned a1 = (unsigned)__shfl((int)pk0_1, srcA);
    unsigned b1 = (unsigned)__shfl((int)pk1_1, srcA);
    unsigned a2 = (unsigned)__shfl((int)pk0_0, srcB);
    unsigned b2 = (unsigned)__shfl((int)pk1_0, srcB);
    unsigned a3 = (unsigned)__shfl((int)pk0_1, srcB);
    unsigned b3 = (unsigned)__shfl((int)pk1_1, srcB);
    o.u[0] = hiT ? b0 : a0;
    o.u[1] = hiT ? b1 : a1;
    o.u[2] = hiT ? b2 : a2;
    o.u[3] = hiT ? b3 : a3;
    return o.v;
}

// Pre-pass: pack W{q,k,v} into per-head bf16 frags wp[which][h][t][ks][lane][8]
// = W[h*32 + 16t + (lane&15)][32ks + (lane>>4)*8 + jj]; and gather the
// rel-pos bias transposed: bias_t[h][n(key) 64][m(query) 64], zero-padded.
__global__ void prep_kernel(const float* __restrict__ Wq,
                            const float* __restrict__ Wk,
                            const float* __restrict__ Wv,
                            const float* __restrict__ table,
                            const int*  __restrict__ ridx,
                            bf16* __restrict__ wp,
                            float* __restrict__ bias_t) {
    int i = blockIdx.x*256 + threadIdx.x;
    if (i < WP_FRAGS) {
        int lane = i & 63, ks = (i >> 6) & 3, t = (i >> 8) & 1;
        int h = (i >> 9) & 3, which = i >> 11;
        const float* W = which == 0 ? Wq : (which == 1 ? Wk : Wv);
        const float* p = W + (h*DHD + t*16 + (lane & 15))*CH + ks*32 + (lane >> 4)*8;
        ((bf16x8*)wp)[i] = pack8(*(const float4*)p, *(const float4*)(p + 4));
    } else {
        int j = i - WP_FRAGS;
        if (j < BIAS_ELEMS) {
            int h = j >> 12, n = (j >> 6) & 63, m = j & 63;
            float v = 0.f;
            if (n < SEQ && m < SEQ) {
                int idx = ridx[m*SEQ + n];
                idx = idx < 0 ? 0 : (idx > NTAB-1 ? NTAB-1 : idx);
                v = table[idx*NH + h];
            }
            bias_t[j] = v;
        }
    }
}

template<bool WS>
__global__ __launch_bounds__(64, 4) void swin_attn_kernel(
    const float* __restrict__ hs,     // [B,49,128]
    const float* __restrict__ amask,  // [B,49,49]
    const float* __restrict__ Wq, const float* __restrict__ bq,
    const float* __restrict__ Wk, const float* __restrict__ bk,
    const float* __restrict__ Wv, const float* __restrict__ bv,
    const float* __restrict__ table,  // [169,4]
    const int*  __restrict__ ridx,    // [2401]
    const bf16*  __restrict__ wp,     // packed W frags (WS)
    const float* __restrict__ bias_t, // [4][64][64]    (WS)
    float* __restrict__ out)          // [B,49,128]
{
    const int b = blockIdx.x >> 2;
    const int h = blockIdx.x & 3;
    const int lane = threadIdx.x & 63;
    const int l = lane & 15;
    const int q = lane >> 4;
    const int srcA = ((q & 1) << 5) | l;
    const int srcB = srcA + 16;
    const bool hiT = q >= 2;

    const float* xb = hs + (size_t)b*SEQ*CH;
    const f32x4 z4 = {0.f, 0.f, 0.f, 0.f};

    // X B/A-frag: X[16rt + l][32ks + 8q + jj], rows clamped to 48 (row>=49
    // garbage is harmless: m-garbage never stored, n-garbage gets P==0).
    auto loadX = [&](int rt, int ks) -> bf16x8 {
        int row = rt*16 + l; row = row > SEQ-1 ? SEQ-1 : row;
        const float* p = xb + row*CH + ks*32 + q*8;
        return pack8(*(const float4*)p, *(const float4*)(p + 4));
    };
    auto loadW = [&](int which, int t, int ks) -> bf16x8 {
        if (WS) {
            return *(const bf16x8*)(wp +
                ((((size_t)(which*NH + h)*2 + t)*4 + ks)*64 + lane)*8);
        } else {
            const float* W = which == 0 ? Wq : (which == 1 ? Wk : Wv);
            const float* p = W + (h*DHD + t*16 + l)*CH + ks*32 + q*8;
            return pack8(*(const float4*)p, *(const float4*)(p + 4));
        }
    };

    // ---- Q^T / K^T projections (swapped: A=W, B=X) -> frags via regroup ----
    bf16x8 fQ[4], fK[4];   // frag rt: [m-or-n = 16rt + l][c = 8q + jj]
#pragma unroll
    for (int which = 0; which < 2; ++which) {
        f32x4 acc[2][4] = {{z4,z4,z4,z4},{z4,z4,z4,z4}};  // [c-tile][row-tile]
#pragma unroll
        for (int ks = 0; ks < 4; ++ks) {
            bf16x8 xf[4];
#pragma unroll
            for (int rt = 0; rt < 4; ++rt) xf[rt] = loadX(rt, ks);
#pragma unroll
            for (int t = 0; t < 2; ++t) {
                const bf16x8 wf = loadW(which, t, ks);
#pragma unroll
                for (int rt = 0; rt < 4; ++rt)
                    acc[t][rt] = __builtin_amdgcn_mfma_f32_16x16x32_bf16(
                        wf, xf[rt], acc[t][rt], 0, 0, 0);
            }
        }
        const float* bvec = which == 0 ? bq : bk;
        unsigned pk[2][4][2];
#pragma unroll
        for (int t = 0; t < 2; ++t) {
            const float b0 = bvec[h*DHD + t*16 + 4*q + 0];
            const float b1 = bvec[h*DHD + t*16 + 4*q + 1];
            const float b2 = bvec[h*DHD + t*16 + 4*q + 2];
            const float b3 = bvec[h*DHD + t*16 + 4*q + 3];
#pragma unroll
            for (int rt = 0; rt < 4; ++rt) {
                pk[t][rt][0] = pk2(acc[t][rt][0] + b0, acc[t][rt][1] + b1);
                pk[t][rt][1] = pk2(acc[t][rt][2] + b2, acc[t][rt][3] + b3);
            }
        }
#pragma unroll
        for (int rt = 0; rt < 4; ++rt) {
            const bf16x8 f = regroup(pk[0][rt][0], pk[0][rt][1],
                                     pk[1][rt][0], pk[1][rt][1], srcA, srcB, hiT);
            if (which == 0) fQ[rt] = f; else fK[rt] = f;
        }
    }

    // ---- V projection (straight: A=X, B=W); bias deferred to epilogue ----
    f32x4 accV[4][2] = {{z4,z4},{z4,z4},{z4,z4},{z4,z4}};  // [n-tile][d-tile]
#pragma unroll
    for (int ks = 0; ks < 4; ++ks) {
        bf16x8 xf[4];
#pragma unroll
        for (int nt = 0; nt < 4; ++nt) xf[nt] = loadX(nt, ks);
#pragma unroll
        for (int dt = 0; dt < 2; ++dt) {
            const bf16x8 wf = loadW(2, dt, ks);
#pragma unroll
            for (int nt = 0; nt < 4; ++nt)
                accV[nt][dt] = __builtin_amdgcn_mfma_f32_16x16x32_bf16(
                    xf[nt], wf, accV[nt][dt], 0, 0, 0);
        }
    }
    unsigned pkv[4][2][2];
#pragma unroll
    for (int nt = 0; nt < 4; ++nt)
#pragma unroll
        for (int dt = 0; dt < 2; ++dt) {
            pkv[nt][dt][0] = pk2(accV[nt][dt][0], accV[nt][dt][1]);
            pkv[nt][dt][1] = pk2(accV[nt][dt][2], accV[nt][dt][3]);
        }
    bf16x8 fV[2][2];   // B-frag: [d = 16dt + l][n = 32ks2 + 8q + jj]
#pragma unroll
    for (int dt = 0; dt < 2; ++dt)
#pragma unroll
        for (int ks2 = 0; ks2 < 2; ++ks2)
            fV[dt][ks2] = regroup(pkv[2*ks2][dt][0],   pkv[2*ks2][dt][1],
                                  pkv[2*ks2+1][dt][0], pkv[2*ks2+1][dt][1],
                                  srcA, srcB, hiT);

    // ---- S^T = K Q^T (swapped): lane holds n = 16kt+4q+r, m = 16qt+l ----
    f32x4 S[4][4];   // [kt][qt]
#pragma unroll
    for (int kt = 0; kt < 4; ++kt)
#pragma unroll
        for (int qt = 0; qt < 4; ++qt)
            S[kt][qt] = __builtin_amdgcn_mfma_f32_16x16x32_bf16(
                fK[kt], fQ[qt], z4, 0, 0, 0);

    // ---- softmax over n (quads + in-lane), P packed for PV ----
    const float scale = 0.17677669529663687f;  // 1/sqrt(32)
    const float* maskb = amask + (size_t)b*SEQ*SEQ;
    const float* biash = WS ? bias_t + h*4096 : nullptr;
    unsigned pkp[4][4][2];
#pragma unroll
    for (int qt = 0; qt < 4; ++qt) {
        const int m = qt*16 + l;
        const int mc = m > SEQ-1 ? SEQ-1 : m;
        float mx = -3.0e38f;
#pragma unroll
        for (int kt = 0; kt < 4; ++kt)
#pragma unroll
            for (int r = 0; r < 4; ++r) {
                const int n = kt*16 + 4*q + r;
                const int nc = n > SEQ-1 ? SEQ-1 : n;
                float bt;
                if (WS) {
                    bt = biash[n*64 + m];           // zero-padded, no clamp
                } else {
                    int idx = ridx[mc*SEQ + nc];
                    idx = idx < 0 ? 0 : (idx > NTAB-1 ? NTAB-1 : idx);
                    bt = table[idx*NH + h];
                }
                const float mk = maskb[mc*SEQ + nc];
                const float s = (n < SEQ) ? S[kt][qt][r]*scale + bt + mk
                                          : -30000.f;
                S[kt][qt][r] = s;
                mx = fmaxf(mx, s);
            }
        mx = fmaxf(mx, __shfl_xor(mx, 16));
        mx = fmaxf(mx, __shfl_xor(mx, 32));
        float sum = 0.f;
#pragma unroll
        for (int kt = 0; kt < 4; ++kt)
#pragma unroll
            for (int r = 0; r < 4; ++r) {
                const float e = __expf(S[kt][qt][r] - mx);
                S[kt][qt][r] = e;
                sum += e;
            }
        sum += __shfl_xor(sum, 16);
        sum += __shfl_xor(sum, 32);
        const float inv = 1.f / sum;
#pragma unroll
        for (int kt = 0; kt < 4; ++kt) {
            pkp[kt][qt][0] = pk2(S[kt][qt][0]*inv, S[kt][qt][1]*inv);
            pkp[kt][qt][1] = pk2(S[kt][qt][2]*inv, S[kt][qt][3]*inv);
        }
    }

    // ---- O = P V ----
    f32x4 O[4][2] = {{z4,z4},{z4,z4},{z4,z4},{z4,z4}};
#pragma unroll
    for (int qt = 0; qt < 4; ++qt)
#pragma unroll
        for (int ks2 = 0; ks2 < 2; ++ks2) {
            const bf16x8 ap = regroup(pkp[2*ks2][qt][0],   pkp[2*ks2][qt][1],
                                      pkp[2*ks2+1][qt][0], pkp[2*ks2+1][qt][1],
                                      srcA, srcB, hiT);
#pragma unroll
            for (int dt = 0; dt < 2; ++dt)
                O[qt][dt] = __builtin_amdgcn_mfma_f32_16x16x32_bf16(
                    ap, fV[dt][ks2], O[qt][dt], 0, 0, 0);
        }

    // epilogue: O rows m = 16qt + 4q + r, cols d = 16dt + l; V-bias added here
    const float bv0 = bv[h*DHD + l];
    const float bv1 = bv[h*DHD + 16 + l];
    float* ob = out + (size_t)b*SEQ*CH + h*DHD;
#pragma unroll
    for (int qt = 0; qt < 4; ++qt)
#pragma unroll
        for (int r = 0; r < 4; ++r) {
            const int m = qt*16 + 4*q + r;
            if (m < SEQ) {
                ob[m*CH + l]      = O[qt][0][r] + bv0;
                ob[m*CH + 16 + l] = O[qt][1][r] + bv1;
            }
        }
}

extern "C" void kernel_launch(void* const* d_in, const int* in_sizes, int n_in,
                              void* d_out, int out_size, void* d_ws, size_t ws_size,
                              hipStream_t stream) {
    (void)n_in; (void)out_size;
    const int nwin = in_sizes[0] / (SEQ * CH);
    const bool usews = (d_ws != nullptr) && (ws_size >= WS_NEED);
    if (usews) {
        bf16* wp = (bf16*)d_ws;
        float* bias_t = (float*)((char*)d_ws + WP_BYTES);
        prep_kernel<<<dim3((WP_FRAGS + BIAS_ELEMS + 255)/256), dim3(256), 0, stream>>>(
            (const float*)d_in[2], (const float*)d_in[4], (const float*)d_in[6],
            (const float*)d_in[8], (const int*)d_in[9], wp, bias_t);
        swin_attn_kernel<true><<<dim3(nwin*NH), dim3(64), 0, stream>>>(
            (const float*)d_in[0], (const float*)d_in[1],
            (const float*)d_in[2], (const float*)d_in[3],
            (const float*)d_in[4], (const float*)d_in[5],
            (const float*)d_in[6], (const float*)d_in[7],
            (const float*)d_in[8], (const int*)d_in[9],
            wp, bias_t, (float*)d_out);
    } else {
        swin_attn_kernel<false><<<dim3(nwin*NH), dim3(64), 0, stream>>>(
            (const float*)d_in[0], (const float*)d_in[1],
            (const float*)d_in[2], (const float*)d_in[3],
            (const float*)d_in[4], (const float*)d_in[5],
            (const float*)d_in[6], (const float*)d_in[7],
            (const float*)d_in[8], (const int*)d_in[9],
            nullptr, nullptr, (float*)d_out);
    }
}